// Round 23
// baseline (39.253 us; speedup 1.0000x reference)
//
#include <hip/hip_runtime.h>
#include <hip/hip_bf16.h>

#define LOG2E 1.4426950408889634f
#define C2    (2.0f * LOG2E)

static __device__ __forceinline__ float fast_exp2(float x) {
#if __has_builtin(__builtin_amdgcn_exp2f)
  return __builtin_amdgcn_exp2f(x);
#else
  return exp2f(x);
#endif
}
static __device__ __forceinline__ float fast_rcp(float x) {
#if __has_builtin(__builtin_amdgcn_rcpf)
  return __builtin_amdgcn_rcpf(x);
#else
  return 1.0f / x;
#endif
}

typedef short bf16x8 __attribute__((ext_vector_type(8)));
typedef float f32x4  __attribute__((ext_vector_type(4)));

static __device__ __forceinline__ short f2bf(float x) {  // RNE f32->bf16
  unsigned u = __float_as_uint(x);
  u += 0x7fff + ((u >> 16) & 1);
  return (short)(u >> 16);
}

// ---------------------------------------------------------------------------
// MFMA projections v2 (r17/r20 — proven).
//   bz=0: qs[q][h] = exp2(C2*(queries@W_q))   f32 row-major (Eq)
//   bz=1: ks_p[((b*64+h/4)*256+k)*4 + h%4] = exp2(C2*(keys@W_k))  (Ek, f32)
// ---------------------------------------------------------------------------
__global__ __launch_bounds__(256, 4) void proj_kernel(
    const float* __restrict__ queries, const float* __restrict__ keys,
    const float* __restrict__ W_q,     const float* __restrict__ W_k,
    const int*   __restrict__ vlen,
    float* __restrict__ qs, float* __restrict__ ks_p)
{
  const int bz = blockIdx.z;
  const float* X = bz ? keys : queries;
  const float* W = bz ? W_k  : W_q;
  const int n0 = blockIdx.x * 32;
  const int m0 = blockIdx.y * 64;

  if (bz == 1) {                      // masked key tiles: skip whole block
    const int vl = vlen[m0 >> 8];
    if ((m0 & 255) >= vl) return;
  }

  const int t = threadIdx.x;
  const int l = t & 63;
  const int w = t >> 6;

  __shared__ short Wp[8 * 2 * 64 * 8];   // [kc][nt][lane][j] bf16, 16 KB

  {
    const int nl = t & 31, ko = t >> 5;
#pragma unroll
    for (int rep = 0; rep < 4; ++rep) {
      const int koct = ko + rep * 8;        // 0..31, k = koct*8 + jj
      const int kc  = koct >> 2;
      const int grp = koct & 3;
      const int nt  = nl >> 4;
      const int ln  = grp * 16 + (nl & 15);
      short w8[8];
#pragma unroll
      for (int jj = 0; jj < 8; ++jj)
        w8[jj] = f2bf(W[(size_t)(koct * 8 + jj) * 256 + n0 + nl]);
      *(bf16x8*)&Wp[((kc * 2 + nt) * 64 + ln) * 8] = *(bf16x8*)w8;
    }
  }
  __syncthreads();

  const int mb   = m0 + w * 16;
  const int row  = mb + (l & 15);
  const int kofs = (l >> 4) * 8;

  f32x4 acc0 = {0.f, 0.f, 0.f, 0.f};
  f32x4 acc1 = {0.f, 0.f, 0.f, 0.f};
#pragma unroll
  for (int kc = 0; kc < 8; ++kc) {
    float4 a0 = *(const float4*)&X[(size_t)row * 256 + kc * 32 + kofs];
    float4 a1 = *(const float4*)&X[(size_t)row * 256 + kc * 32 + kofs + 4];
    bf16x8 af;
    af[0] = f2bf(a0.x); af[1] = f2bf(a0.y); af[2] = f2bf(a0.z); af[3] = f2bf(a0.w);
    af[4] = f2bf(a1.x); af[5] = f2bf(a1.y); af[6] = f2bf(a1.z); af[7] = f2bf(a1.w);
    bf16x8 b0 = *(bf16x8*)&Wp[((kc * 2 + 0) * 64 + l) * 8];
    bf16x8 b1 = *(bf16x8*)&Wp[((kc * 2 + 1) * 64 + l) * 8];
    acc0 = __builtin_amdgcn_mfma_f32_16x16x32_bf16(af, b0, acc0, 0, 0, 0);
    acc1 = __builtin_amdgcn_mfma_f32_16x16x32_bf16(af, b1, acc1, 0, 0, 0);
  }

  const int c = l & 15;
#pragma unroll
  for (int nt = 0; nt < 2; ++nt) {
    const f32x4 acc = nt ? acc1 : acc0;
    const int n = n0 + nt * 16 + c;
#pragma unroll
    for (int j = 0; j < 4; ++j) {
      const int rj = (l >> 4) * 4 + j;
      const float o = fast_exp2(acc[j] * C2);
      if (bz == 0) {
        qs[(size_t)(mb + rj) * 256 + n] = o;
      } else {
        const int b  = mb >> 8;
        const int kl = (mb & 255) + rj;
        ks_p[((size_t)(b * 64 + (n >> 2)) * 256 + kl) * 4 + (n & 3)] = o;
      }
    }
  }
}

// ---------------------------------------------------------------------------
// Score inner loop with QUAD rcp fusion (r21/r22):
//   sum_i w_i/t_i over 4 h = (n01*t23 + n23*t01) * rcp(t01*t23),
//   t_i = fma(eq_i, ek_i, 1) >= 1.  Per 4 elems: 14 VALU + 1 rcp.
// ---------------------------------------------------------------------------
#define SC_QUAD_Q(qv, qi)                                                  \
  {                                                                        \
    float t0 = fmaf(qv.x, kv[j].x, 1.f);                                   \
    float t1 = fmaf(qv.y, kv[j].y, 1.f);                                   \
    float t2 = fmaf(qv.z, kv[j].z, 1.f);                                   \
    float t3 = fmaf(qv.w, kv[j].w, 1.f);                                   \
    float t01 = t0 * t1, t23 = t2 * t3;                                    \
    float n01 = fmaf(wv.x, t1, wv.y * t0);                                 \
    float n23 = fmaf(wv.z, t3, wv.w * t2);                                 \
    float num = fmaf(n01, t23, n23 * t01);                                 \
    sc[j][qi] = fmaf(num, fast_rcp(t01 * t23), sc[j][qi]);                 \
  }

template <int NJ>
__device__ __forceinline__ void score_loop(
    const float* __restrict__ kp,    // ks_p + b*65536 + lane*4
    const float* __restrict__ qp,    // qs + (b*256+q0)*256 (4 rows)
    const float* __restrict__ wvp, int h4b, float (&sc)[4][4])
{
#pragma unroll 2
  for (int h4 = h4b; h4 < h4b + 8; ++h4) {
    float4 kv[NJ];
#pragma unroll
    for (int j = 0; j < NJ; ++j)
      kv[j] = *(const float4*)(kp + h4 * 1024 + j * 256);
    float4 qv0 = *(const float4*)(qp + 0 * 256 + h4 * 4);  // uniform s_loads
    float4 qv1 = *(const float4*)(qp + 1 * 256 + h4 * 4);
    float4 qv2 = *(const float4*)(qp + 2 * 256 + h4 * 4);
    float4 qv3 = *(const float4*)(qp + 3 * 256 + h4 * 4);
    float4 wv  = *(const float4*)(wvp + h4 * 4);
#pragma unroll
    for (int j = 0; j < NJ; ++j) {
      SC_QUAD_Q(qv0, 0); SC_QUAD_Q(qv1, 1);
      SC_QUAD_Q(qv2, 2); SC_QUAD_Q(qv3, 3);
    }
  }
}

// ---------------------------------------------------------------------------
// Fused scores + softmax + PV, v13 = r22 + TWO-ROUND LDS reductions.
// LDS 36.2 -> 20.1 KB: score partials and PV partials each reduced in two
// rounds (waves 4-7 write a 16 KB slab; barrier; waves 0-3 add their own
// in place) — softmax / final-reduce then read 4 slots, not 8.
// launch_bounds(512, 6) -> 3 blocks/CU = 6 waves/SIMD (was 2 blocks, 4/SIMD)
// at IDENTICAL traffic — clean occupancy test (r19's was confounded).
// ---------------------------------------------------------------------------
__global__ __launch_bounds__(512, 6) void attn_kernel(
    const float* __restrict__ qs, const float* __restrict__ ks_p,
    const float* __restrict__ values, const int* __restrict__ vlen,
    const float* __restrict__ w_v, float* __restrict__ out)
{
  const int t    = threadIdx.x;
  const int lane = t & 63;
  const int w    = t >> 6;                 // h-eighth / PV k-parity 0..7
  const int bx   = blockIdx.x;

  // ---- sorted complementary batch pairing (all-scalar, deterministic) ----
  int njv[8];
#pragma unroll
  for (int i = 0; i < 8; ++i) njv[i] = (vlen[i] + 63) >> 6;
  unsigned packed = 0, rem = 0xFFu;
#pragma unroll
  for (int r = 0; r < 8; ++r) {            // selection sort, nj desc, idx asc
    int best = -1, bi = 0;
#pragma unroll
    for (int i = 0; i < 8; ++i) {
      if (rem & (1u << i)) {
        int key = njv[i] * 8 + (7 - i);
        if (key > best) { best = key; bi = i; }
      }
    }
    packed |= (unsigned)bi << (3 * r);
    rem &= ~(1u << bi);
  }
  const int jpair = bx & 3;
  const int hi    = (bx >> 8) & 1;
  const int sel   = hi ? (7 - jpair) : jpair;
  const int b     = (int)((packed >> (3 * sel)) & 7u);
  const int q0    = ((bx >> 2) & 63) * 4;

  __shared__ __align__(16) float sbuf[4096];   // 16 KB shared exchange slab
  __shared__ __align__(16) float p2[256 * 4];  // 4 KB [k][q]
  __shared__ float rsum_lds[4];

  const int vl = vlen[b];
  const int nj = (vl + 63) >> 6;

  // Wsum = sum(w_v)
  float s0 = w_v[lane] + w_v[lane + 64] + w_v[lane + 128] + w_v[lane + 192];
#pragma unroll
  for (int off = 32; off; off >>= 1) s0 += __shfl_xor(s0, off);
  const float Wsum = s0;

  const float* qp = qs + (size_t)(b * 256 + q0) * 256;   // 4 rows, uniform
  const float* kp = ks_p + (size_t)b * 65536 + lane * 4;
  const int h4b = w * 8;

  float sc[4][4] = {};
  switch (nj) {
    case 1:  score_loop<1>(kp, qp, w_v, h4b, sc); break;
    case 2:  score_loop<2>(kp, qp, w_v, h4b, sc); break;
    case 3:  score_loop<3>(kp, qp, w_v, h4b, sc); break;
    default: score_loop<4>(kp, qp, w_v, h4b, sc); break;
  }

  // score exchange, round A: waves 4-7 write [w-4][j][lane][q]
  if (w >= 4) {
#pragma unroll
    for (int j = 0; j < 4; ++j)
      *(float4*)&sbuf[(((w - 4) * 4 + j) * 64 + lane) * 4] =
          make_float4(sc[j][0], sc[j][1], sc[j][2], sc[j][3]);
  }

  // EARLY V-ISSUE (independent of p2): latency hides under softmax
  const float* Vb = values + (size_t)b * 65536 + lane * 4;
  float4 v0 = make_float4(0.f, 0.f, 0.f, 0.f);
  float4 v1 = make_float4(0.f, 0.f, 0.f, 0.f);
  if (w < vl)     v0 = *(const float4*)(Vb + (size_t)w * 256);
  if (w + 8 < vl) v1 = *(const float4*)(Vb + (size_t)(w + 8) * 256);
  __syncthreads();

  // round B: waves 0-3 add their own partials in place
  if (w < 4) {
#pragma unroll
    for (int j = 0; j < 4; ++j) {
      float4 o = *(const float4*)&sbuf[((w * 4 + j) * 64 + lane) * 4];
      o.x += sc[j][0]; o.y += sc[j][1]; o.z += sc[j][2]; o.w += sc[j][3];
      *(float4*)&sbuf[((w * 4 + j) * 64 + lane) * 4] = o;
    }
  }
  __syncthreads();

  // softmax: waves 0-3, wave q owns q-row q0+q; sums 4 slots
  if (w < 4) {
    const int q = w;
    float scores[4];
    float mx = -3.4e38f;
#pragma unroll 4
    for (int j = 0; j < nj; ++j) {
      float s = sbuf[((0 * 4 + j) * 64 + lane) * 4 + q] +
                sbuf[((1 * 4 + j) * 64 + lane) * 4 + q] +
                sbuf[((2 * 4 + j) * 64 + lane) * 4 + q] +
                sbuf[((3 * 4 + j) * 64 + lane) * 4 + q];
      float v = Wsum - 2.f * s;
      if (j * 64 + lane >= vl) v = -1000000.0f;
      scores[j] = v;
      mx = fmaxf(mx, v);
    }
#pragma unroll
    for (int off = 32; off; off >>= 1) mx = fmaxf(mx, __shfl_xor(mx, off));
    float sum = 0.f;
#pragma unroll 4
    for (int j = 0; j < nj; ++j) {
      float p = fast_exp2((scores[j] - mx) * LOG2E);
      p2[(j * 64 + lane) * 4 + q] = p;
      sum += p;
    }
#pragma unroll
    for (int off = 32; off; off >>= 1) sum += __shfl_xor(sum, off);
    if (lane == 0) rsum_lds[q] = sum;
  }
  __syncthreads();                        // score reads done; p2/rsum ready

  // PV: wave w takes k == w (mod 8); 4 q-accums per V load; depth-2 prefetch
  float4 acc[4];
#pragma unroll
  for (int q = 0; q < 4; ++q) acc[q] = make_float4(0.f, 0.f, 0.f, 0.f);
  if (w < vl) {
    for (int k = w; k < vl; k += 8) {
      float4 vn = (k + 16 < vl)
                      ? *(const float4*)(Vb + (size_t)(k + 16) * 256)
                      : make_float4(0.f, 0.f, 0.f, 0.f);
      float4 pk = *(const float4*)&p2[k * 4];        // b128 LDS broadcast
      acc[0].x = fmaf(pk.x, v0.x, acc[0].x);
      acc[0].y = fmaf(pk.x, v0.y, acc[0].y);
      acc[0].z = fmaf(pk.x, v0.z, acc[0].z);
      acc[0].w = fmaf(pk.x, v0.w, acc[0].w);
      acc[1].x = fmaf(pk.y, v0.x, acc[1].x);
      acc[1].y = fmaf(pk.y, v0.y, acc[1].y);
      acc[1].z = fmaf(pk.y, v0.z, acc[1].z);
      acc[1].w = fmaf(pk.y, v0.w, acc[1].w);
      acc[2].x = fmaf(pk.z, v0.x, acc[2].x);
      acc[2].y = fmaf(pk.z, v0.y, acc[2].y);
      acc[2].z = fmaf(pk.z, v0.z, acc[2].z);
      acc[2].w = fmaf(pk.z, v0.w, acc[2].w);
      acc[3].x = fmaf(pk.w, v0.x, acc[3].x);
      acc[3].y = fmaf(pk.w, v0.y, acc[3].y);
      acc[3].z = fmaf(pk.w, v0.z, acc[3].z);
      acc[3].w = fmaf(pk.w, v0.w, acc[3].w);
      v0 = v1; v1 = vn;
    }
  }

  // PV exchange, round A: waves 4-7 write [w-4][q][256]
  if (w >= 4) {
#pragma unroll
    for (int q = 0; q < 4; ++q)
      *(float4*)&sbuf[((w - 4) * 4 + q) * 256 + lane * 4] = acc[q];
  }
  __syncthreads();
  // round B: waves 0-3 add theirs in place
  if (w < 4) {
#pragma unroll
    for (int q = 0; q < 4; ++q) {
      float4 o = *(const float4*)&sbuf[(w * 4 + q) * 256 + lane * 4];
      o.x += acc[q].x; o.y += acc[q].y; o.z += acc[q].z; o.w += acc[q].w;
      *(float4*)&sbuf[(w * 4 + q) * 256 + lane * 4] = o;
    }
  }
  __syncthreads();

  // final reduce: 512 thr x 2 -> 4q x 256d; sums 4 slots
#pragma unroll
  for (int rep = 0; rep < 2; ++rep) {
    int o = t + rep * 512;
    int q = o >> 8, d = o & 255;
    float s = sbuf[(0 * 4 + q) * 256 + d] + sbuf[(1 * 4 + q) * 256 + d] +
              sbuf[(2 * 4 + q) * 256 + d] + sbuf[(3 * 4 + q) * 256 + d];
    out[(size_t)(b * 256 + q0 + q) * 256 + d] = s * fast_rcp(rsum_lds[q]);
  }
}

extern "C" void kernel_launch(void* const* d_in, const int* in_sizes, int n_in,
                              void* d_out, int out_size, void* d_ws, size_t ws_size,
                              hipStream_t stream) {
  const float* queries = (const float*)d_in[0];
  const float* keys    = (const float*)d_in[1];
  const float* values  = (const float*)d_in[2];
  const int*   vlenp   = (const int*)d_in[3];
  const float* W_q     = (const float*)d_in[4];
  const float* W_k     = (const float*)d_in[5];
  const float* w_v     = (const float*)d_in[6];
  float* out = (float*)d_out;

  float* qs   = (float*)d_ws;               // 2 MiB, Eq f32 row-major [m][256]
  float* ks_p = qs + 2048 * 256;            // 2 MiB, Ek f32 packed [b][h/4][k][4]

  dim3 pgrid(8, 32, 2);                     // (n-strips of 32, m-tiles, matrix)
  proj_kernel<<<pgrid, 256, 0, stream>>>(queries, keys, W_q, W_k, vlenp, qs, ks_p);
  attn_kernel<<<512, 512, 0, stream>>>(qs, ks_p, values, vlenp, w_v, out);
}

// Round 26
// 32.808 us; speedup vs baseline: 1.1965x; 1.1965x over previous
//
#include <hip/hip_runtime.h>
#include <hip/hip_bf16.h>

#define LOG2E 1.4426950408889634f
#define C2    (2.0f * LOG2E)

static __device__ __forceinline__ float fast_exp2(float x) {
#if __has_builtin(__builtin_amdgcn_exp2f)
  return __builtin_amdgcn_exp2f(x);
#else
  return exp2f(x);
#endif
}
static __device__ __forceinline__ float fast_rcp(float x) {
#if __has_builtin(__builtin_amdgcn_rcpf)
  return __builtin_amdgcn_rcpf(x);
#else
  return 1.0f / x;
#endif
}

typedef short bf16x8 __attribute__((ext_vector_type(8)));
typedef float f32x4  __attribute__((ext_vector_type(4)));

static __device__ __forceinline__ short f2bf(float x) {  // RNE f32->bf16
  unsigned u = __float_as_uint(x);
  u += 0x7fff + ((u >> 16) & 1);
  return (short)(u >> 16);
}

// ---------------------------------------------------------------------------
// MFMA projections v2 (r17/r20 — proven).
//   bz=0: qs[q][h] = exp2(C2*(queries@W_q))   f32 row-major (Eq)
//   bz=1: ks_p[((b*64+h/4)*256+k)*4 + h%4] = exp2(C2*(keys@W_k))  (Ek, f32)
// ---------------------------------------------------------------------------
__global__ __launch_bounds__(256, 4) void proj_kernel(
    const float* __restrict__ queries, const float* __restrict__ keys,
    const float* __restrict__ W_q,     const float* __restrict__ W_k,
    const int*   __restrict__ vlen,
    float* __restrict__ qs, float* __restrict__ ks_p)
{
  const int bz = blockIdx.z;
  const float* X = bz ? keys : queries;
  const float* W = bz ? W_k  : W_q;
  const int n0 = blockIdx.x * 32;
  const int m0 = blockIdx.y * 64;

  if (bz == 1) {                      // masked key tiles: skip whole block
    const int vl = vlen[m0 >> 8];
    if ((m0 & 255) >= vl) return;
  }

  const int t = threadIdx.x;
  const int l = t & 63;
  const int w = t >> 6;

  __shared__ short Wp[8 * 2 * 64 * 8];   // [kc][nt][lane][j] bf16, 16 KB

  {
    const int nl = t & 31, ko = t >> 5;
#pragma unroll
    for (int rep = 0; rep < 4; ++rep) {
      const int koct = ko + rep * 8;        // 0..31, k = koct*8 + jj
      const int kc  = koct >> 2;
      const int grp = koct & 3;
      const int nt  = nl >> 4;
      const int ln  = grp * 16 + (nl & 15);
      short w8[8];
#pragma unroll
      for (int jj = 0; jj < 8; ++jj)
        w8[jj] = f2bf(W[(size_t)(koct * 8 + jj) * 256 + n0 + nl]);
      *(bf16x8*)&Wp[((kc * 2 + nt) * 64 + ln) * 8] = *(bf16x8*)w8;
    }
  }
  __syncthreads();

  const int mb   = m0 + w * 16;
  const int row  = mb + (l & 15);
  const int kofs = (l >> 4) * 8;

  f32x4 acc0 = {0.f, 0.f, 0.f, 0.f};
  f32x4 acc1 = {0.f, 0.f, 0.f, 0.f};
#pragma unroll
  for (int kc = 0; kc < 8; ++kc) {
    float4 a0 = *(const float4*)&X[(size_t)row * 256 + kc * 32 + kofs];
    float4 a1 = *(const float4*)&X[(size_t)row * 256 + kc * 32 + kofs + 4];
    bf16x8 af;
    af[0] = f2bf(a0.x); af[1] = f2bf(a0.y); af[2] = f2bf(a0.z); af[3] = f2bf(a0.w);
    af[4] = f2bf(a1.x); af[5] = f2bf(a1.y); af[6] = f2bf(a1.z); af[7] = f2bf(a1.w);
    bf16x8 b0 = *(bf16x8*)&Wp[((kc * 2 + 0) * 64 + l) * 8];
    bf16x8 b1 = *(bf16x8*)&Wp[((kc * 2 + 1) * 64 + l) * 8];
    acc0 = __builtin_amdgcn_mfma_f32_16x16x32_bf16(af, b0, acc0, 0, 0, 0);
    acc1 = __builtin_amdgcn_mfma_f32_16x16x32_bf16(af, b1, acc1, 0, 0, 0);
  }

  const int c = l & 15;
#pragma unroll
  for (int nt = 0; nt < 2; ++nt) {
    const f32x4 acc = nt ? acc1 : acc0;
    const int n = n0 + nt * 16 + c;
#pragma unroll
    for (int j = 0; j < 4; ++j) {
      const int rj = (l >> 4) * 4 + j;
      const float o = fast_exp2(acc[j] * C2);
      if (bz == 0) {
        qs[(size_t)(mb + rj) * 256 + n] = o;
      } else {
        const int b  = mb >> 8;
        const int kl = (mb & 255) + rj;
        ks_p[((size_t)(b * 64 + (n >> 2)) * 256 + kl) * 4 + (n & 3)] = o;
      }
    }
  }
}

// ---------------------------------------------------------------------------
// Score inner loop with QUAD rcp fusion:
//   sum_i w_i/t_i over 4 h = (n01*t23 + n23*t01) * rcp(t01*t23),
//   t_i = fma(eq_i, ek_i, 1) >= 1.  Per 4 elems: 14 VALU + 1 rcp.
// Wave = h-eighth (8 h4 iters); kv amortized over 4 q-rows.
// ---------------------------------------------------------------------------
#define SC_QUAD_Q(qv, qi)                                                  \
  {                                                                        \
    float t0 = fmaf(qv.x, kv[j].x, 1.f);                                   \
    float t1 = fmaf(qv.y, kv[j].y, 1.f);                                   \
    float t2 = fmaf(qv.z, kv[j].z, 1.f);                                   \
    float t3 = fmaf(qv.w, kv[j].w, 1.f);                                   \
    float t01 = t0 * t1, t23 = t2 * t3;                                    \
    float n01 = fmaf(wv.x, t1, wv.y * t0);                                 \
    float n23 = fmaf(wv.z, t3, wv.w * t2);                                 \
    float num = fmaf(n01, t23, n23 * t01);                                 \
    sc[j][qi] = fmaf(num, fast_rcp(t01 * t23), sc[j][qi]);                 \
  }

template <int NJ>
__device__ __forceinline__ void score_loop(
    const float* __restrict__ kp,    // ks_p + b*65536 + lane*4
    const float* __restrict__ qp,    // qs + (b*256+q0)*256 (4 rows)
    const float* __restrict__ wvp, int h4b, float (&sc)[4][4])
{
#pragma unroll 2
  for (int h4 = h4b; h4 < h4b + 8; ++h4) {
    float4 kv[NJ];
#pragma unroll
    for (int j = 0; j < NJ; ++j)
      kv[j] = *(const float4*)(kp + h4 * 1024 + j * 256);
    float4 qv0 = *(const float4*)(qp + 0 * 256 + h4 * 4);  // uniform s_loads
    float4 qv1 = *(const float4*)(qp + 1 * 256 + h4 * 4);
    float4 qv2 = *(const float4*)(qp + 2 * 256 + h4 * 4);
    float4 qv3 = *(const float4*)(qp + 3 * 256 + h4 * 4);
    float4 wv  = *(const float4*)(wvp + h4 * 4);
#pragma unroll
    for (int j = 0; j < NJ; ++j) {
      SC_QUAD_Q(qv0, 0); SC_QUAD_Q(qv1, 1);
      SC_QUAD_Q(qv2, 2); SC_QUAD_Q(qv3, 3);
    }
  }
}

// ---------------------------------------------------------------------------
// Fused scores + softmax + PV (r22 verbatim: sorted complementary pairing +
// quad fusion + early V-issue + depth-2 PV; softmax sums ALL 8 wave slots —
// the r24/r25 failures were a carried 4-slot read from r23's two-round
// variant, dropping h in [128,256) from every score).
// ---------------------------------------------------------------------------
__global__ __launch_bounds__(512, 4) void attn_kernel(
    const float* __restrict__ qs, const float* __restrict__ ks_p,
    const float* __restrict__ values, const int* __restrict__ vlen,
    const float* __restrict__ w_v, float* __restrict__ out)
{
  const int t    = threadIdx.x;
  const int lane = t & 63;
  const int w    = t >> 6;                 // h-eighth / PV k-parity 0..7
  const int bx   = blockIdx.x;

  // ---- sorted complementary batch pairing (all-scalar, deterministic) ----
  int njv[8];
#pragma unroll
  for (int i = 0; i < 8; ++i) njv[i] = (vlen[i] + 63) >> 6;
  unsigned packed = 0, rem = 0xFFu;
#pragma unroll
  for (int r = 0; r < 8; ++r) {            // selection sort, nj desc, idx asc
    int best = -1, bi = 0;
#pragma unroll
    for (int i = 0; i < 8; ++i) {
      if (rem & (1u << i)) {
        int key = njv[i] * 8 + (7 - i);
        if (key > best) { best = key; bi = i; }
      }
    }
    packed |= (unsigned)bi << (3 * r);
    rem &= ~(1u << bi);
  }
  const int jpair = bx & 3;
  const int hi    = (bx >> 8) & 1;
  const int sel   = hi ? (7 - jpair) : jpair;
  const int b     = (int)((packed >> (3 * sel)) & 7u);
  const int q0    = ((bx >> 2) & 63) * 4;

  __shared__ __align__(16) float sbuf[8192];   // 32 KB: score parts [w][j][lane][q]
                                               // reused: PV parts [w][q][256]
  __shared__ __align__(16) float p2[256 * 4];  // 4 KB [k][q]
  __shared__ float rsum_lds[4];

  const int vl = vlen[b];
  const int nj = (vl + 63) >> 6;

  // Wsum = sum(w_v)
  float s0 = w_v[lane] + w_v[lane + 64] + w_v[lane + 128] + w_v[lane + 192];
#pragma unroll
  for (int off = 32; off; off >>= 1) s0 += __shfl_xor(s0, off);
  const float Wsum = s0;

  const float* qp = qs + (size_t)(b * 256 + q0) * 256;   // 4 rows, uniform
  const float* kp = ks_p + (size_t)b * 65536 + lane * 4;
  const int h4b = w * 8;

  float sc[4][4] = {};
  switch (nj) {
    case 1:  score_loop<1>(kp, qp, w_v, h4b, sc); break;
    case 2:  score_loop<2>(kp, qp, w_v, h4b, sc); break;
    case 3:  score_loop<3>(kp, qp, w_v, h4b, sc); break;
    default: score_loop<4>(kp, qp, w_v, h4b, sc); break;
  }

  // write partials: sbuf[((w*4 + j)*64 + lane)*4 + q]  (b128, conflict-free)
#pragma unroll
  for (int j = 0; j < 4; ++j)
    *(float4*)&sbuf[((w * 4 + j) * 64 + lane) * 4] =
        make_float4(sc[j][0], sc[j][1], sc[j][2], sc[j][3]);

  // EARLY V-ISSUE: first two PV loads (independent of p2) — latency hides
  // under the softmax phase.
  const float* Vb = values + (size_t)b * 65536 + lane * 4;
  float4 v0 = make_float4(0.f, 0.f, 0.f, 0.f);
  float4 v1 = make_float4(0.f, 0.f, 0.f, 0.f);
  if (w < vl)     v0 = *(const float4*)(Vb + (size_t)w * 256);
  if (w + 8 < vl) v1 = *(const float4*)(Vb + (size_t)(w + 8) * 256);
  __syncthreads();

  // softmax: waves 0-3, wave q owns q-row q0+q; sums ALL 8 wave slots
  if (w < 4) {
    const int q = w;
    float scores[4];
    float mx = -3.4e38f;
#pragma unroll 4
    for (int j = 0; j < nj; ++j) {
      float s = 0.f;
#pragma unroll
      for (int ww = 0; ww < 8; ++ww)
        s += sbuf[((ww * 4 + j) * 64 + lane) * 4 + q];
      float v = Wsum - 2.f * s;
      if (j * 64 + lane >= vl) v = -1000000.0f;
      scores[j] = v;
      mx = fmaxf(mx, v);
    }
#pragma unroll
    for (int off = 32; off; off >>= 1) mx = fmaxf(mx, __shfl_xor(mx, off));
    float sum = 0.f;
#pragma unroll 4
    for (int j = 0; j < nj; ++j) {
      float p = fast_exp2((scores[j] - mx) * LOG2E);
      p2[(j * 64 + lane) * 4 + q] = p;
      sum += p;
    }
#pragma unroll
    for (int off = 32; off; off >>= 1) sum += __shfl_xor(sum, off);
    if (lane == 0) rsum_lds[q] = sum;
  }
  __syncthreads();                        // sbuf reads done; p2/rsum ready

  // PV: wave w takes k == w (mod 8); 4 q-accums per V load; depth-2 prefetch
  float4 acc[4];
#pragma unroll
  for (int q = 0; q < 4; ++q) acc[q] = make_float4(0.f, 0.f, 0.f, 0.f);
  if (w < vl) {
    for (int k = w; k < vl; k += 8) {
      float4 vn = (k + 16 < vl)
                      ? *(const float4*)(Vb + (size_t)(k + 16) * 256)
                      : make_float4(0.f, 0.f, 0.f, 0.f);
      float4 pk = *(const float4*)&p2[k * 4];        // b128 LDS broadcast
      acc[0].x = fmaf(pk.x, v0.x, acc[0].x);
      acc[0].y = fmaf(pk.x, v0.y, acc[0].y);
      acc[0].z = fmaf(pk.x, v0.z, acc[0].z);
      acc[0].w = fmaf(pk.x, v0.w, acc[0].w);
      acc[1].x = fmaf(pk.y, v0.x, acc[1].x);
      acc[1].y = fmaf(pk.y, v0.y, acc[1].y);
      acc[1].z = fmaf(pk.y, v0.z, acc[1].z);
      acc[1].w = fmaf(pk.y, v0.w, acc[1].w);
      acc[2].x = fmaf(pk.z, v0.x, acc[2].x);
      acc[2].y = fmaf(pk.z, v0.y, acc[2].y);
      acc[2].z = fmaf(pk.z, v0.z, acc[2].z);
      acc[2].w = fmaf(pk.z, v0.w, acc[2].w);
      acc[3].x = fmaf(pk.w, v0.x, acc[3].x);
      acc[3].y = fmaf(pk.w, v0.y, acc[3].y);
      acc[3].z = fmaf(pk.w, v0.z, acc[3].z);
      acc[3].w = fmaf(pk.w, v0.w, acc[3].w);
      v0 = v1; v1 = vn;
    }
  }
  // PV partials reuse sbuf: [w][q][256]
#pragma unroll
  for (int q = 0; q < 4; ++q)
    *(float4*)&sbuf[(w * 4 + q) * 256 + lane * 4] = acc[q];
  __syncthreads();

  // final reduce: 512 thr x 2 -> 4q x 256d
#pragma unroll
  for (int rep = 0; rep < 2; ++rep) {
    int o = t + rep * 512;
    int q = o >> 8, d = o & 255;
    float s = 0.f;
#pragma unroll
    for (int ww = 0; ww < 8; ++ww) s += sbuf[(ww * 4 + q) * 256 + d];
    out[(size_t)(b * 256 + q0 + q) * 256 + d] = s * fast_rcp(rsum_lds[q]);
  }
}

extern "C" void kernel_launch(void* const* d_in, const int* in_sizes, int n_in,
                              void* d_out, int out_size, void* d_ws, size_t ws_size,
                              hipStream_t stream) {
  const float* queries = (const float*)d_in[0];
  const float* keys    = (const float*)d_in[1];
  const float* values  = (const float*)d_in[2];
  const int*   vlenp   = (const int*)d_in[3];
  const float* W_q     = (const float*)d_in[4];
  const float* W_k     = (const float*)d_in[5];
  const float* w_v     = (const float*)d_in[6];
  float* out = (float*)d_out;

  float* qs   = (float*)d_ws;               // 2 MiB, Eq f32 row-major [m][256]
  float* ks_p = qs + 2048 * 256;            // 2 MiB, Ek f32 packed [b][h/4][k][4]

  dim3 pgrid(8, 32, 2);                     // (n-strips of 32, m-tiles, matrix)
  proj_kernel<<<pgrid, 256, 0, stream>>>(queries, keys, W_q, W_k, vlenp, qs, ks_p);
  attn_kernel<<<512, 512, 0, stream>>>(qs, ks_p, values, vlenp, w_v, out);
}